// Round 1
// baseline (5255.397 us; speedup 1.0000x reference)
//
#include <hip/hip_runtime.h>

// LightGCN: 3-layer propagation over a 200001-node graph, EMB_DIM=64.
// acc lives in d_out with node->row map r = (n<=100000) ? n : n+1
// (row 100001 is item_out[0] == 0). 1/4 scale folded into accumulation.

#define N_NODES 200001
#define NUP1    100001   // NUM_USERS + 1
#define D       64
#define DV      16       // float4s per row

__global__ __launch_bounds__(256) void init_kernel(
    const float4* __restrict__ user_emb,
    const float4* __restrict__ item_emb,
    float4* __restrict__ x,
    float4* __restrict__ out) {
  int idx = blockIdx.x * 256 + threadIdx.x;
  if (idx < DV) {
    // zero item_out row 0 (output row NUP1)
    out[(size_t)NUP1 * DV + idx] = make_float4(0.f, 0.f, 0.f, 0.f);
  }
  if (idx >= N_NODES * DV) return;
  int n = idx >> 4;          // node
  int j = idx & 15;          // float4 index within row
  float4 v = (n < NUP1) ? user_emb[idx]
                        : item_emb[(size_t)(n - 100000) * DV + j];
  x[idx] = v;
  int r = (n < NUP1) ? n : n + 1;
  float4 s;
  s.x = 0.25f * v.x; s.y = 0.25f * v.y; s.z = 0.25f * v.z; s.w = 0.25f * v.w;
  out[(size_t)r * DV + j] = s;
}

// Edge-parallel SpMM: 16 lanes per edge, each lane handles one float4 of the
// 64-dim row. Hardware f32 atomics into y.
__global__ __launch_bounds__(256) void spmm_kernel(
    const int*    __restrict__ rows,
    const int*    __restrict__ cols,
    const float*  __restrict__ vals,
    const float4* __restrict__ x,
    float*        __restrict__ y,
    int nnz) {
  int t = blockIdx.x * 256 + threadIdx.x;
  int e = t >> 4;
  int j = t & 15;
  if (e >= nnz) return;
  int   r = rows[e];
  int   c = cols[e];
  float v = vals[e];
  float4 xv = x[(size_t)c * DV + j];
  float* yp = y + (size_t)r * D + j * 4;
  unsafeAtomicAdd(yp + 0, v * xv.x);
  unsafeAtomicAdd(yp + 1, v * xv.y);
  unsafeAtomicAdd(yp + 2, v * xv.z);
  unsafeAtomicAdd(yp + 3, v * xv.w);
}

// acc (in d_out, row-mapped) += 0.25 * y
__global__ __launch_bounds__(256) void add_acc_kernel(
    const float4* __restrict__ y,
    float4* __restrict__ out) {
  int idx = blockIdx.x * 256 + threadIdx.x;
  if (idx >= N_NODES * DV) return;
  int n = idx >> 4;
  int j = idx & 15;
  int r = (n < NUP1) ? n : n + 1;
  float4 a = out[(size_t)r * DV + j];
  float4 b = y[idx];
  a.x += 0.25f * b.x; a.y += 0.25f * b.y;
  a.z += 0.25f * b.z; a.w += 0.25f * b.w;
  out[(size_t)r * DV + j] = a;
}

extern "C" void kernel_launch(void* const* d_in, const int* in_sizes, int n_in,
                              void* d_out, int out_size, void* d_ws, size_t ws_size,
                              hipStream_t stream) {
  const float* user_emb = (const float*)d_in[0];
  const float* item_emb = (const float*)d_in[1];
  const int*   rows     = (const int*)d_in[2];
  const int*   cols     = (const int*)d_in[3];
  const float* vals     = (const float*)d_in[4];
  const int    nnz      = in_sizes[2];

  float* xa  = (float*)d_ws;
  float* xb  = xa + (size_t)N_NODES * D;
  float* out = (float*)d_out;

  const int row_elems = N_NODES * DV;            // 3,200,016 float4 slots
  const int init_grid = (row_elems + 255) / 256;

  init_kernel<<<init_grid, 256, 0, stream>>>(
      (const float4*)user_emb, (const float4*)item_emb,
      (float4*)xa, (float4*)out);

  float* xin  = xa;
  float* xout = xb;
  const size_t xbytes = (size_t)N_NODES * D * sizeof(float);
  const long long spmm_threads = (long long)nnz * 16;
  const int spmm_grid = (int)((spmm_threads + 255) / 256);

  for (int l = 0; l < 3; ++l) {
    hipMemsetAsync(xout, 0, xbytes, stream);
    spmm_kernel<<<spmm_grid, 256, 0, stream>>>(
        rows, cols, vals, (const float4*)xin, xout, nnz);
    add_acc_kernel<<<init_grid, 256, 0, stream>>>(
        (const float4*)xout, (float4*)out);
    float* tmp = xin; xin = xout; xout = tmp;
  }
}

// Round 2
// 650.121 us; speedup vs baseline: 8.0837x; 8.0837x over previous
//
#include <hip/hip_runtime.h>

// LightGCN, 3-layer propagation, 200001 nodes, D=64.
// Round 2: device-built CSR (histogram + 2-level scan + scatter) replaces
// 384M memory-side f32 atomics with row-parallel gather SpMM (zero atomics),
// with the acc += 0.25*y pass fused into the SpMM epilogue.

#define N_NODES 200001
#define NUP1    100001            // NUM_USERS + 1
#define D       64
#define DV      16                // float4s per row
#define CHUNK   2048
#define NCHUNK  ((N_NODES + CHUNK - 1) / CHUNK)   // 98

__global__ __launch_bounds__(256) void init_kernel(
    const float4* __restrict__ user_emb,
    const float4* __restrict__ item_emb,
    float4* __restrict__ x,
    float4* __restrict__ out) {
  int idx = blockIdx.x * 256 + threadIdx.x;
  if (idx < DV) {
    out[(size_t)NUP1 * DV + idx] = make_float4(0.f, 0.f, 0.f, 0.f);
  }
  if (idx >= N_NODES * DV) return;
  int n = idx >> 4;
  int j = idx & 15;
  float4 v = (n < NUP1) ? user_emb[idx]
                        : item_emb[(size_t)(n - 100000) * DV + j];
  x[idx] = v;
  int r = (n < NUP1) ? n : n + 1;
  float4 s;
  s.x = 0.25f * v.x; s.y = 0.25f * v.y; s.z = 0.25f * v.z; s.w = 0.25f * v.w;
  out[(size_t)r * DV + j] = s;
}

__global__ __launch_bounds__(256) void hist_kernel(
    const int* __restrict__ rows, int* __restrict__ count, int nnz) {
  int e = blockIdx.x * 256 + threadIdx.x;
  if (e < nnz) atomicAdd(&count[rows[e]], 1);
}

// Per-chunk sums (chunk = 2048 counts, 256 threads x 8 each).
__global__ __launch_bounds__(256) void chunk_sum_kernel(
    const int* __restrict__ count, int* __restrict__ chunk_sums) {
  __shared__ int red[256];
  int t = threadIdx.x;
  int base = blockIdx.x * CHUNK + t * 8;
  int s = 0;
#pragma unroll
  for (int k = 0; k < 8; ++k) {
    int idx = base + k;
    s += (idx < N_NODES) ? count[idx] : 0;
  }
  red[t] = s;
  __syncthreads();
  for (int off = 128; off > 0; off >>= 1) {
    if (t < off) red[t] += red[t + off];
    __syncthreads();
  }
  if (t == 0) chunk_sums[blockIdx.x] = red[0];
}

// Serial exclusive scan over 98 chunk sums; also writes row_ptr[N] = total.
__global__ void scan_chunks_kernel(int* __restrict__ chunk_sums,
                                   int* __restrict__ row_ptr) {
  if (threadIdx.x == 0 && blockIdx.x == 0) {
    int run = 0;
    for (int i = 0; i < NCHUNK; ++i) {
      int c = chunk_sums[i];
      chunk_sums[i] = run;
      run += c;
    }
    row_ptr[N_NODES] = run;
  }
}

// Exclusive scan within each chunk + chunk offset -> row_ptr & cursor.
__global__ __launch_bounds__(256) void scan_within_kernel(
    const int* __restrict__ count, const int* __restrict__ chunk_off,
    int* __restrict__ row_ptr, int* __restrict__ cursor) {
  __shared__ int tsum[256];
  int t = threadIdx.x;
  int base = blockIdx.x * CHUNK + t * 8;
  int local[8];
  int s = 0;
#pragma unroll
  for (int k = 0; k < 8; ++k) {
    int idx = base + k;
    int c = (idx < N_NODES) ? count[idx] : 0;
    local[k] = c;
    s += c;
  }
  tsum[t] = s;
  __syncthreads();
  for (int off = 1; off < 256; off <<= 1) {
    int v = (t >= off) ? tsum[t - off] : 0;
    __syncthreads();
    tsum[t] += v;
    __syncthreads();
  }
  int run = tsum[t] - s + chunk_off[blockIdx.x];   // exclusive prefix
#pragma unroll
  for (int k = 0; k < 8; ++k) {
    int idx = base + k;
    if (idx < N_NODES) {
      row_ptr[idx] = run;
      cursor[idx] = run;
    }
    run += local[k];
  }
}

// Scatter edges into CSR order as packed (col, val_bits).
__global__ __launch_bounds__(256) void scatter_kernel(
    const int* __restrict__ rows, const int* __restrict__ cols,
    const float* __restrict__ vals, int* __restrict__ cursor,
    int2* __restrict__ edge_s, int nnz) {
  int e = blockIdx.x * 256 + threadIdx.x;
  if (e >= nnz) return;
  int r = rows[e];
  int p = atomicAdd(&cursor[r], 1);
  edge_s[p] = make_int2(cols[e], __float_as_int(vals[e]));
}

// Row-parallel SpMM, 16 lanes per row (one float4 each), fused epilogue:
// y[r] = sum, out[rowmap(r)] += 0.25*sum. No atomics.
__global__ __launch_bounds__(256) void spmm_fused_kernel(
    const int*    __restrict__ row_ptr,
    const int2*   __restrict__ edge_s,
    const float4* __restrict__ x,
    float4*       __restrict__ y,
    float4*       __restrict__ out) {
  int t = blockIdx.x * 256 + threadIdx.x;
  int r = t >> 4;
  int j = t & 15;
  if (r >= N_NODES) return;
  int s = row_ptr[r];
  int e = row_ptr[r + 1];
  float4 acc = make_float4(0.f, 0.f, 0.f, 0.f);
  for (int k = s; k < e; ++k) {
    int2 ed = edge_s[k];
    float v = __int_as_float(ed.y);
    float4 xv = x[(size_t)ed.x * DV + j];
    acc.x += v * xv.x; acc.y += v * xv.y;
    acc.z += v * xv.z; acc.w += v * xv.w;
  }
  y[t] = acc;
  int rm = (r < NUP1) ? r : r + 1;
  size_t oi = (size_t)rm * DV + j;
  float4 o = out[oi];
  o.x += 0.25f * acc.x; o.y += 0.25f * acc.y;
  o.z += 0.25f * acc.z; o.w += 0.25f * acc.w;
  out[oi] = o;
}

static inline char* align16(char* p) {
  return (char*)(((uintptr_t)p + 15) & ~(uintptr_t)15);
}

extern "C" void kernel_launch(void* const* d_in, const int* in_sizes, int n_in,
                              void* d_out, int out_size, void* d_ws, size_t ws_size,
                              hipStream_t stream) {
  const float* user_emb = (const float*)d_in[0];
  const float* item_emb = (const float*)d_in[1];
  const int*   rows     = (const int*)d_in[2];
  const int*   cols     = (const int*)d_in[3];
  const float* vals     = (const float*)d_in[4];
  const int    nnz      = in_sizes[2];

  // Workspace carve-up (~121 MB total).
  char* p = (char*)d_ws;
  float* xa = (float*)p;      p += (size_t)N_NODES * D * sizeof(float);
  float* xb = (float*)p;      p += (size_t)N_NODES * D * sizeof(float);
  p = align16(p);
  int2* edge_s = (int2*)p;    p += (size_t)nnz * sizeof(int2);
  p = align16(p);
  int* row_ptr = (int*)p;     p += (size_t)(N_NODES + 1) * sizeof(int);
  p = align16(p);
  int* count = (int*)p;       p += (size_t)N_NODES * sizeof(int);
  p = align16(p);
  int* cursor = (int*)p;      p += (size_t)N_NODES * sizeof(int);
  p = align16(p);
  int* chunk_sums = (int*)p;  p += (size_t)NCHUNK * sizeof(int);

  float* out = (float*)d_out;

  const int row_elems = N_NODES * DV;              // 3,200,016
  const int node_grid = (row_elems + 255) / 256;   // 12501
  const int edge_grid = (nnz + 255) / 256;         // 7813

  // --- CSR build (once per call) ---
  hipMemsetAsync(count, 0, (size_t)N_NODES * sizeof(int), stream);
  init_kernel<<<node_grid, 256, 0, stream>>>(
      (const float4*)user_emb, (const float4*)item_emb,
      (float4*)xa, (float4*)out);
  hist_kernel<<<edge_grid, 256, 0, stream>>>(rows, count, nnz);
  chunk_sum_kernel<<<NCHUNK, 256, 0, stream>>>(count, chunk_sums);
  scan_chunks_kernel<<<1, 64, 0, stream>>>(chunk_sums, row_ptr);
  scan_within_kernel<<<NCHUNK, 256, 0, stream>>>(count, chunk_sums, row_ptr, cursor);
  scatter_kernel<<<edge_grid, 256, 0, stream>>>(rows, cols, vals, cursor, edge_s, nnz);

  // --- 3 propagation layers, fused accumulate ---
  float* xin = xa;
  float* xout = xb;
  for (int l = 0; l < 3; ++l) {
    spmm_fused_kernel<<<node_grid, 256, 0, stream>>>(
        row_ptr, (const int2*)edge_s, (const float4*)xin,
        (float4*)xout, (float4*)out);
    float* tmp = xin; xin = xout; xout = tmp;
  }
}

// Round 3
// 510.649 us; speedup vs baseline: 10.2916x; 1.2731x over previous
//
#include <hip/hip_runtime.h>

// LightGCN, 3-layer propagation, 200001 nodes, D=64.
// Round 3: cache-resident two-pass counting sort for the CSR build.
// pass1: tile multisplit into 98 chunk-buckets (private per-block runs ->
//        full-line writebacks). hist+scatter then operate per-chunk with
//        LDS histograms / LDS cursors (zero per-edge global atomics) and
//        L2-resident destination windows.

#define N_NODES 200001
#define NUP1    100001            // NUM_USERS + 1
#define D       64
#define DV      16                // float4s per row
#define CHUNK   2048
#define NCHUNK  ((N_NODES + CHUNK - 1) / CHUNK)   // 98
#define T_TILE  4096              // edges per pass1 block
#define EPT     16                // edges per thread in pass1
#define CAP     24576             // bucket capacity (exp 20480, +28 sigma)

__global__ __launch_bounds__(256) void init_kernel(
    const float4* __restrict__ user_emb,
    const float4* __restrict__ item_emb,
    float4* __restrict__ x,
    float4* __restrict__ out) {
  int idx = blockIdx.x * 256 + threadIdx.x;
  if (idx < DV) {
    out[(size_t)NUP1 * DV + idx] = make_float4(0.f, 0.f, 0.f, 0.f);
  }
  if (idx >= N_NODES * DV) return;
  int n = idx >> 4;
  int j = idx & 15;
  float4 v = (n < NUP1) ? user_emb[idx]
                        : item_emb[(size_t)(n - 100000) * DV + j];
  x[idx] = v;
  int r = (n < NUP1) ? n : n + 1;
  float4 s;
  s.x = 0.25f * v.x; s.y = 0.25f * v.y; s.z = 0.25f * v.z; s.w = 0.25f * v.w;
  out[(size_t)r * DV + j] = s;
}

// Pass 1: multisplit edges into 98 chunk-buckets. Each block reserves one
// contiguous run per bucket (few global atomics), writes its run densely.
__global__ __launch_bounds__(256) void pass1_bucket(
    const int*   __restrict__ rows,
    const int*   __restrict__ cols,
    const float* __restrict__ vals,
    int*  __restrict__ bucket_cnt,
    int2* __restrict__ bucket_arr,
    int nnz) {
  __shared__ int lcount[NCHUNK];
  __shared__ int lbase[NCHUNK];
  int t = threadIdx.x;
  for (int i = t; i < NCHUNK; i += 256) lcount[i] = 0;
  __syncthreads();
  long base = (long)blockIdx.x * T_TILE;
  int2 pk[EPT];
  int  meta[EPT];
#pragma unroll
  for (int k = 0; k < EPT; ++k) {
    long e = base + t + (long)k * 256;
    if (e < nnz) {
      int r = rows[e];
      int b = r >> 11;                         // chunk bucket (0..97)
      int rank = atomicAdd(&lcount[b], 1);     // LDS atomic
      pk[k] = make_int2(((r & 2047) << 18) | cols[e], __float_as_int(vals[e]));
      meta[k] = (rank << 7) | b;               // rank<4096 (12b) | b (7b)
    } else {
      meta[k] = -1;
    }
  }
  __syncthreads();
  for (int b = t; b < NCHUNK; b += 256) {
    int c = lcount[b];
    lbase[b] = (c > 0) ? (b * CAP + atomicAdd(&bucket_cnt[b], c)) : 0;
  }
  __syncthreads();
#pragma unroll
  for (int k = 0; k < EPT; ++k) {
    if (meta[k] >= 0) {
      int b = meta[k] & 127;
      int rank = meta[k] >> 7;
      bucket_arr[lbase[b] + rank] = pk[k];
    }
  }
}

// Per-chunk row histogram from the bucketed (contiguous) edges. LDS atomics.
__global__ __launch_bounds__(256) void hist_chunk_kernel(
    const int*  __restrict__ bucket_cnt,
    const int2* __restrict__ bucket_arr,
    int* __restrict__ count) {
  __shared__ int lcnt[CHUNK];
  int b = blockIdx.x, t = threadIdx.x;
  for (int i = t; i < CHUNK; i += 256) lcnt[i] = 0;
  __syncthreads();
  int ne = bucket_cnt[b];
  const int2* ba = bucket_arr + (size_t)b * CAP;
  for (int i = t; i < ne; i += 256)
    atomicAdd(&lcnt[ba[i].x >> 18], 1);
  __syncthreads();
  for (int i = t; i < CHUNK; i += 256)
    count[b * CHUNK + i] = lcnt[i];
}

// Serial exclusive scan over 98 bucket counts -> chunk offsets; total -> row_ptr[N].
__global__ void scan_chunks_kernel(const int* __restrict__ cnt,
                                   int* __restrict__ off,
                                   int* __restrict__ row_ptr) {
  if (threadIdx.x == 0 && blockIdx.x == 0) {
    int run = 0;
    for (int i = 0; i < NCHUNK; ++i) { off[i] = run; run += cnt[i]; }
    row_ptr[N_NODES] = run;
  }
}

// Exclusive scan within each chunk + chunk offset -> row_ptr.
__global__ __launch_bounds__(256) void scan_within_kernel(
    const int* __restrict__ count, const int* __restrict__ chunk_off,
    int* __restrict__ row_ptr) {
  __shared__ int tsum[256];
  int t = threadIdx.x;
  int base = blockIdx.x * CHUNK + t * 8;
  int local[8];
  int s = 0;
#pragma unroll
  for (int k = 0; k < 8; ++k) {
    int idx = base + k;
    int c = (idx < N_NODES) ? count[idx] : 0;
    local[k] = c;
    s += c;
  }
  tsum[t] = s;
  __syncthreads();
  for (int off = 1; off < 256; off <<= 1) {
    int v = (t >= off) ? tsum[t - off] : 0;
    __syncthreads();
    tsum[t] += v;
    __syncthreads();
  }
  int run = tsum[t] - s + chunk_off[blockIdx.x];
#pragma unroll
  for (int k = 0; k < 8; ++k) {
    int idx = base + k;
    if (idx < N_NODES) row_ptr[idx] = run;
    run += local[k];
  }
}

// Pass 2: per-chunk scatter into final CSR order. LDS cursors, L2-resident
// ~164 KB destination window per block.
__global__ __launch_bounds__(256) void pass2_scatter(
    const int*  __restrict__ bucket_cnt,
    const int2* __restrict__ bucket_arr,
    const int*  __restrict__ row_ptr,
    int2* __restrict__ edge_s) {
  __shared__ int lcur[CHUNK];
  int b = blockIdx.x, t = threadIdx.x;
  int row0 = b * CHUNK;
  for (int i = t; i < CHUNK; i += 256) {
    int idx = row0 + i;
    lcur[i] = (idx < N_NODES) ? row_ptr[idx] : 0;
  }
  __syncthreads();
  int ne = bucket_cnt[b];
  const int2* ba = bucket_arr + (size_t)b * CAP;
  for (int i = t; i < ne; i += 256) {
    int2 ed = ba[i];
    int p = atomicAdd(&lcur[ed.x >> 18], 1);   // LDS atomic
    edge_s[p] = make_int2(ed.x & 0x3FFFF, ed.y);
  }
}

// Row-parallel SpMM, 16 lanes per row, fused out += 0.25*y epilogue.
__global__ __launch_bounds__(256) void spmm_fused_kernel(
    const int*    __restrict__ row_ptr,
    const int2*   __restrict__ edge_s,
    const float4* __restrict__ x,
    float4*       __restrict__ y,
    float4*       __restrict__ out) {
  int t = blockIdx.x * 256 + threadIdx.x;
  int r = t >> 4;
  int j = t & 15;
  if (r >= N_NODES) return;
  int s = row_ptr[r];
  int e = row_ptr[r + 1];
  float4 acc = make_float4(0.f, 0.f, 0.f, 0.f);
  for (int k = s; k < e; ++k) {
    int2 ed = edge_s[k];
    float v = __int_as_float(ed.y);
    float4 xv = x[(size_t)ed.x * DV + j];
    acc.x += v * xv.x; acc.y += v * xv.y;
    acc.z += v * xv.z; acc.w += v * xv.w;
  }
  y[t] = acc;
  int rm = (r < NUP1) ? r : r + 1;
  size_t oi = (size_t)rm * DV + j;
  float4 o = out[oi];
  o.x += 0.25f * acc.x; o.y += 0.25f * acc.y;
  o.z += 0.25f * acc.z; o.w += 0.25f * acc.w;
  out[oi] = o;
}

static inline char* align16(char* p) {
  return (char*)(((uintptr_t)p + 15) & ~(uintptr_t)15);
}

extern "C" void kernel_launch(void* const* d_in, const int* in_sizes, int n_in,
                              void* d_out, int out_size, void* d_ws, size_t ws_size,
                              hipStream_t stream) {
  const float* user_emb = (const float*)d_in[0];
  const float* item_emb = (const float*)d_in[1];
  const int*   rows     = (const int*)d_in[2];
  const int*   cols     = (const int*)d_in[3];
  const float* vals     = (const float*)d_in[4];
  const int    nnz      = in_sizes[2];

  char* p = (char*)d_ws;
  float* xa = (float*)p;      p += (size_t)N_NODES * D * sizeof(float);
  float* xb = (float*)p;      p += (size_t)N_NODES * D * sizeof(float);
  // bucket_arr aliases xb: consumed by pass2 before spmm layer 1 writes xb.
  int2* bucket_arr = (int2*)xb;   // 98 * 24576 * 8 B = 19.3 MB <= 51.2 MB
  p = align16(p);
  int2* edge_s = (int2*)p;    p += (size_t)nnz * sizeof(int2);
  p = align16(p);
  int* row_ptr = (int*)p;     p += (size_t)(N_NODES + 1) * sizeof(int);
  p = align16(p);
  int* count = (int*)p;       p += (size_t)NCHUNK * CHUNK * sizeof(int);
  p = align16(p);
  int* chunk_off = (int*)p;   p += (size_t)NCHUNK * sizeof(int);
  p = align16(p);
  int* bucket_cnt = (int*)p;  p += (size_t)NCHUNK * sizeof(int);

  float* out = (float*)d_out;

  const int row_elems = N_NODES * DV;              // 3,200,016
  const int node_grid = (row_elems + 255) / 256;   // 12501
  const int tile_grid = (nnz + T_TILE - 1) / T_TILE;

  hipMemsetAsync(bucket_cnt, 0, (size_t)NCHUNK * sizeof(int), stream);
  init_kernel<<<node_grid, 256, 0, stream>>>(
      (const float4*)user_emb, (const float4*)item_emb,
      (float4*)xa, (float4*)out);
  pass1_bucket<<<tile_grid, 256, 0, stream>>>(
      rows, cols, vals, bucket_cnt, bucket_arr, nnz);
  hist_chunk_kernel<<<NCHUNK, 256, 0, stream>>>(bucket_cnt, bucket_arr, count);
  scan_chunks_kernel<<<1, 64, 0, stream>>>(bucket_cnt, chunk_off, row_ptr);
  scan_within_kernel<<<NCHUNK, 256, 0, stream>>>(count, chunk_off, row_ptr);
  pass2_scatter<<<NCHUNK, 256, 0, stream>>>(bucket_cnt, bucket_arr, row_ptr, edge_s);

  float* xin = xa;
  float* xout = xb;
  for (int l = 0; l < 3; ++l) {
    spmm_fused_kernel<<<node_grid, 256, 0, stream>>>(
        row_ptr, (const int2*)edge_s, (const float4*)xin,
        (float4*)xout, (float4*)out);
    float* tmp = xin; xin = xout; xout = tmp;
  }
}

// Round 4
// 463.437 us; speedup vs baseline: 11.3400x; 1.1019x over previous
//
#include <hip/hip_runtime.h>

// LightGCN, 3-layer propagation, 200001 nodes, D=64.
// Round 4: bf16 inter-layer buffers (halves gather + y-write traffic),
// deferred accumulation (single final pass replaces 3x out-RMW).
// CSR build (two-pass cache-resident counting sort) unchanged from round 3.

#define N_NODES 200001
#define NUP1    100001            // NUM_USERS + 1
#define D       64
#define DV      16                // 16 lanes per row; fp32: float4, bf16: ushort4
#define CHUNK   2048
#define NCHUNK  ((N_NODES + CHUNK - 1) / CHUNK)   // 98
#define T_TILE  4096              // edges per pass1 block
#define EPT     16                // edges per thread in pass1
#define CAP     24576             // bucket capacity (exp 20480, +28 sigma)

__device__ __forceinline__ unsigned short f2bf(float f) {
  unsigned u = __float_as_uint(f);
  unsigned r = (u + 0x7FFFu + ((u >> 16) & 1u)) >> 16;   // RNE
  return (unsigned short)r;
}
__device__ __forceinline__ float bf2f(unsigned short h) {
  return __uint_as_float(((unsigned)h) << 16);
}

// Build x0 (bf16) from fp32 embeddings. No out write here.
__global__ __launch_bounds__(256) void init_kernel(
    const float4* __restrict__ user_emb,
    const float4* __restrict__ item_emb,
    ushort4* __restrict__ x0) {
  int idx = blockIdx.x * 256 + threadIdx.x;
  if (idx >= N_NODES * DV) return;
  int n = idx >> 4;
  int j = idx & 15;
  float4 v = (n < NUP1) ? user_emb[idx]
                        : item_emb[(size_t)(n - 100000) * DV + j];
  x0[idx] = make_ushort4(f2bf(v.x), f2bf(v.y), f2bf(v.z), f2bf(v.w));
}

// Pass 1: multisplit edges into 98 chunk-buckets (private per-block runs).
__global__ __launch_bounds__(256) void pass1_bucket(
    const int*   __restrict__ rows,
    const int*   __restrict__ cols,
    const float* __restrict__ vals,
    int*  __restrict__ bucket_cnt,
    int2* __restrict__ bucket_arr,
    int nnz) {
  __shared__ int lcount[NCHUNK];
  __shared__ int lbase[NCHUNK];
  int t = threadIdx.x;
  for (int i = t; i < NCHUNK; i += 256) lcount[i] = 0;
  __syncthreads();
  long base = (long)blockIdx.x * T_TILE;
  int2 pk[EPT];
  int  meta[EPT];
#pragma unroll
  for (int k = 0; k < EPT; ++k) {
    long e = base + t + (long)k * 256;
    if (e < nnz) {
      int r = rows[e];
      int b = r >> 11;                         // chunk bucket (0..97)
      int rank = atomicAdd(&lcount[b], 1);     // LDS atomic
      pk[k] = make_int2(((r & 2047) << 18) | cols[e], __float_as_int(vals[e]));
      meta[k] = (rank << 7) | b;
    } else {
      meta[k] = -1;
    }
  }
  __syncthreads();
  for (int b = t; b < NCHUNK; b += 256) {
    int c = lcount[b];
    lbase[b] = (c > 0) ? (b * CAP + atomicAdd(&bucket_cnt[b], c)) : 0;
  }
  __syncthreads();
#pragma unroll
  for (int k = 0; k < EPT; ++k) {
    if (meta[k] >= 0) {
      int b = meta[k] & 127;
      int rank = meta[k] >> 7;
      bucket_arr[lbase[b] + rank] = pk[k];
    }
  }
}

// Per-chunk row histogram (LDS atomics).
__global__ __launch_bounds__(256) void hist_chunk_kernel(
    const int*  __restrict__ bucket_cnt,
    const int2* __restrict__ bucket_arr,
    int* __restrict__ count) {
  __shared__ int lcnt[CHUNK];
  int b = blockIdx.x, t = threadIdx.x;
  for (int i = t; i < CHUNK; i += 256) lcnt[i] = 0;
  __syncthreads();
  int ne = bucket_cnt[b];
  const int2* ba = bucket_arr + (size_t)b * CAP;
  for (int i = t; i < ne; i += 256)
    atomicAdd(&lcnt[ba[i].x >> 18], 1);
  __syncthreads();
  for (int i = t; i < CHUNK; i += 256)
    count[b * CHUNK + i] = lcnt[i];
}

__global__ void scan_chunks_kernel(const int* __restrict__ cnt,
                                   int* __restrict__ off,
                                   int* __restrict__ row_ptr) {
  if (threadIdx.x == 0 && blockIdx.x == 0) {
    int run = 0;
    for (int i = 0; i < NCHUNK; ++i) { off[i] = run; run += cnt[i]; }
    row_ptr[N_NODES] = run;
  }
}

__global__ __launch_bounds__(256) void scan_within_kernel(
    const int* __restrict__ count, const int* __restrict__ chunk_off,
    int* __restrict__ row_ptr) {
  __shared__ int tsum[256];
  int t = threadIdx.x;
  int base = blockIdx.x * CHUNK + t * 8;
  int local[8];
  int s = 0;
#pragma unroll
  for (int k = 0; k < 8; ++k) {
    int idx = base + k;
    int c = (idx < N_NODES) ? count[idx] : 0;
    local[k] = c;
    s += c;
  }
  tsum[t] = s;
  __syncthreads();
  for (int off = 1; off < 256; off <<= 1) {
    int v = (t >= off) ? tsum[t - off] : 0;
    __syncthreads();
    tsum[t] += v;
    __syncthreads();
  }
  int run = tsum[t] - s + chunk_off[blockIdx.x];
#pragma unroll
  for (int k = 0; k < 8; ++k) {
    int idx = base + k;
    if (idx < N_NODES) row_ptr[idx] = run;
    run += local[k];
  }
}

// Pass 2: per-chunk scatter into final CSR order (LDS cursors).
__global__ __launch_bounds__(256) void pass2_scatter(
    const int*  __restrict__ bucket_cnt,
    const int2* __restrict__ bucket_arr,
    const int*  __restrict__ row_ptr,
    int2* __restrict__ edge_s) {
  __shared__ int lcur[CHUNK];
  int b = blockIdx.x, t = threadIdx.x;
  int row0 = b * CHUNK;
  for (int i = t; i < CHUNK; i += 256) {
    int idx = row0 + i;
    lcur[i] = (idx < N_NODES) ? row_ptr[idx] : 0;
  }
  __syncthreads();
  int ne = bucket_cnt[b];
  const int2* ba = bucket_arr + (size_t)b * CAP;
  for (int i = t; i < ne; i += 256) {
    int2 ed = ba[i];
    int p = atomicAdd(&lcur[ed.x >> 18], 1);
    edge_s[p] = make_int2(ed.x & 0x3FFFF, ed.y);
  }
}

// Row-parallel bf16 SpMM: 16 lanes per row, each lane owns 4 of 64 dims.
// Gathers 8 B/lane (ushort4), fp32 accumulate, bf16 store. No out update.
__global__ __launch_bounds__(256) void spmm_bf16_kernel(
    const int*     __restrict__ row_ptr,
    const int2*    __restrict__ edge_s,
    const ushort4* __restrict__ x,
    ushort4*       __restrict__ y) {
  int t = blockIdx.x * 256 + threadIdx.x;
  int r = t >> 4;
  int j = t & 15;
  if (r >= N_NODES) return;
  int s = row_ptr[r];
  int e = row_ptr[r + 1];
  float a0 = 0.f, a1 = 0.f, a2 = 0.f, a3 = 0.f;
  for (int k = s; k < e; ++k) {
    int2 ed = edge_s[k];
    float v = __int_as_float(ed.y);
    ushort4 xv = x[(size_t)ed.x * DV + j];
    a0 += v * bf2f(xv.x); a1 += v * bf2f(xv.y);
    a2 += v * bf2f(xv.z); a3 += v * bf2f(xv.w);
  }
  y[t] = make_ushort4(f2bf(a0), f2bf(a1), f2bf(a2), f2bf(a3));
}

// Final: out[rowmap(n)] = 0.25*(x0_fp32 + y1 + y2 + y3); zero item row 0.
__global__ __launch_bounds__(256) void final_kernel(
    const float4*  __restrict__ user_emb,
    const float4*  __restrict__ item_emb,
    const ushort4* __restrict__ y1,
    const ushort4* __restrict__ y2,
    const ushort4* __restrict__ y3,
    float4* __restrict__ out) {
  int idx = blockIdx.x * 256 + threadIdx.x;
  if (idx < DV) {
    out[(size_t)NUP1 * DV + idx] = make_float4(0.f, 0.f, 0.f, 0.f);
  }
  if (idx >= N_NODES * DV) return;
  int n = idx >> 4;
  int j = idx & 15;
  float4 v = (n < NUP1) ? user_emb[idx]
                        : item_emb[(size_t)(n - 100000) * DV + j];
  ushort4 a = y1[idx], b = y2[idx], c = y3[idx];
  float4 o;
  o.x = 0.25f * (v.x + bf2f(a.x) + bf2f(b.x) + bf2f(c.x));
  o.y = 0.25f * (v.y + bf2f(a.y) + bf2f(b.y) + bf2f(c.y));
  o.z = 0.25f * (v.z + bf2f(a.z) + bf2f(b.z) + bf2f(c.z));
  o.w = 0.25f * (v.w + bf2f(a.w) + bf2f(b.w) + bf2f(c.w));
  int rm = (n < NUP1) ? n : n + 1;
  out[(size_t)rm * DV + j] = o;
}

static inline char* align16(char* p) {
  return (char*)(((uintptr_t)p + 15) & ~(uintptr_t)15);
}

extern "C" void kernel_launch(void* const* d_in, const int* in_sizes, int n_in,
                              void* d_out, int out_size, void* d_ws, size_t ws_size,
                              hipStream_t stream) {
  const float* user_emb = (const float*)d_in[0];
  const float* item_emb = (const float*)d_in[1];
  const int*   rows     = (const int*)d_in[2];
  const int*   cols     = (const int*)d_in[3];
  const float* vals     = (const float*)d_in[4];
  const int    nnz      = in_sizes[2];

  const size_t xbytes = (size_t)N_NODES * D * sizeof(unsigned short); // 25.6 MB
  char* p = (char*)d_ws;
  ushort4* x0 = (ushort4*)p;  p += xbytes;
  ushort4* y1 = (ushort4*)p;  p += xbytes;
  ushort4* y2 = (ushort4*)p;  p += xbytes;
  ushort4* y3 = (ushort4*)p;  p += xbytes;
  // bucket_arr aliases y2+y3 (51.2 MB window; needs 19.3 MB): consumed by
  // pass2 before layer-2 spmm writes y2.
  int2* bucket_arr = (int2*)y2;
  p = align16(p);
  int2* edge_s = (int2*)p;    p += (size_t)nnz * sizeof(int2);
  p = align16(p);
  int* row_ptr = (int*)p;     p += (size_t)(N_NODES + 1) * sizeof(int);
  p = align16(p);
  int* count = (int*)p;       p += (size_t)NCHUNK * CHUNK * sizeof(int);
  p = align16(p);
  int* chunk_off = (int*)p;   p += (size_t)NCHUNK * sizeof(int);
  p = align16(p);
  int* bucket_cnt = (int*)p;  p += (size_t)NCHUNK * sizeof(int);

  float* out = (float*)d_out;

  const int row_elems = N_NODES * DV;              // 3,200,016
  const int node_grid = (row_elems + 255) / 256;   // 12501
  const int tile_grid = (nnz + T_TILE - 1) / T_TILE;

  hipMemsetAsync(bucket_cnt, 0, (size_t)NCHUNK * sizeof(int), stream);
  init_kernel<<<node_grid, 256, 0, stream>>>(
      (const float4*)user_emb, (const float4*)item_emb, x0);
  pass1_bucket<<<tile_grid, 256, 0, stream>>>(
      rows, cols, vals, bucket_cnt, bucket_arr, nnz);
  hist_chunk_kernel<<<NCHUNK, 256, 0, stream>>>(bucket_cnt, bucket_arr, count);
  scan_chunks_kernel<<<1, 64, 0, stream>>>(bucket_cnt, chunk_off, row_ptr);
  scan_within_kernel<<<NCHUNK, 256, 0, stream>>>(count, chunk_off, row_ptr);
  pass2_scatter<<<NCHUNK, 256, 0, stream>>>(bucket_cnt, bucket_arr, row_ptr, edge_s);

  spmm_bf16_kernel<<<node_grid, 256, 0, stream>>>(row_ptr, edge_s, x0, y1);
  spmm_bf16_kernel<<<node_grid, 256, 0, stream>>>(row_ptr, edge_s, y1, y2);
  spmm_bf16_kernel<<<node_grid, 256, 0, stream>>>(row_ptr, edge_s, y2, y3);

  final_kernel<<<node_grid, 256, 0, stream>>>(
      (const float4*)user_emb, (const float4*)item_emb, y1, y2, y3,
      (float4*)out);
}

// Round 5
// 364.708 us; speedup vs baseline: 14.4099x; 1.2707x over previous
//
#include <hip/hip_runtime.h>

// LightGCN, 3-layer propagation, 200001 nodes, D=64.
// Round 5: spmm gets 8 lanes/row x 16B gathers + 4-wide manual unroll
// (4 independent gathers in flight per wave). CSR build fused:
// init(+cnt clear) -> pass1 -> scan_chunks -> build_csr_chunk(hist+scan+scatter).

#define N_NODES 200001
#define NUP1    100001            // NUM_USERS + 1
#define D       64
#define DV      16                // float4/ushort4 per row (init/final)
#define DV8     8                 // uint4 (8 bf16) per row (spmm)
#define CHUNK   2048
#define NCHUNK  ((N_NODES + CHUNK - 1) / CHUNK)   // 98
#define T_TILE  4096              // edges per pass1 block
#define EPT     16                // edges per thread in pass1
#define CAP     24576             // bucket capacity (exp 20480, +28 sigma)

__device__ __forceinline__ unsigned short f2bf(float f) {
  unsigned u = __float_as_uint(f);
  unsigned r = (u + 0x7FFFu + ((u >> 16) & 1u)) >> 16;   // RNE
  return (unsigned short)r;
}
__device__ __forceinline__ float bf2f(unsigned short h) {
  return __uint_as_float(((unsigned)h) << 16);
}
// bf16 pair in a uint: low = bits 0..15, high = bits 16..31.
__device__ __forceinline__ float bflo(unsigned u) { return __uint_as_float(u << 16); }
__device__ __forceinline__ float bfhi(unsigned u) { return __uint_as_float(u & 0xFFFF0000u); }

// Build x0 (bf16) from fp32 embeddings; also zero bucket_cnt.
__global__ __launch_bounds__(256) void init_kernel(
    const float4* __restrict__ user_emb,
    const float4* __restrict__ item_emb,
    ushort4* __restrict__ x0,
    int* __restrict__ bucket_cnt) {
  int idx = blockIdx.x * 256 + threadIdx.x;
  if (idx < NCHUNK) bucket_cnt[idx] = 0;
  if (idx >= N_NODES * DV) return;
  int n = idx >> 4;
  int j = idx & 15;
  float4 v = (n < NUP1) ? user_emb[idx]
                        : item_emb[(size_t)(n - 100000) * DV + j];
  x0[idx] = make_ushort4(f2bf(v.x), f2bf(v.y), f2bf(v.z), f2bf(v.w));
}

// Pass 1: multisplit edges into 98 chunk-buckets (private per-block runs).
__global__ __launch_bounds__(256) void pass1_bucket(
    const int*   __restrict__ rows,
    const int*   __restrict__ cols,
    const float* __restrict__ vals,
    int*  __restrict__ bucket_cnt,
    int2* __restrict__ bucket_arr,
    int nnz) {
  __shared__ int lcount[NCHUNK];
  __shared__ int lbase[NCHUNK];
  int t = threadIdx.x;
  for (int i = t; i < NCHUNK; i += 256) lcount[i] = 0;
  __syncthreads();
  long base = (long)blockIdx.x * T_TILE;
  int2 pk[EPT];
  int  meta[EPT];
#pragma unroll
  for (int k = 0; k < EPT; ++k) {
    long e = base + t + (long)k * 256;
    if (e < nnz) {
      int r = rows[e];
      int b = r >> 11;                         // chunk bucket (0..97)
      int rank = atomicAdd(&lcount[b], 1);     // LDS atomic
      pk[k] = make_int2(((r & 2047) << 18) | cols[e], __float_as_int(vals[e]));
      meta[k] = (rank << 7) | b;
    } else {
      meta[k] = -1;
    }
  }
  __syncthreads();
  for (int b = t; b < NCHUNK; b += 256) {
    int c = lcount[b];
    lbase[b] = (c > 0) ? (b * CAP + atomicAdd(&bucket_cnt[b], c)) : 0;
  }
  __syncthreads();
#pragma unroll
  for (int k = 0; k < EPT; ++k) {
    if (meta[k] >= 0) {
      int b = meta[k] & 127;
      int rank = meta[k] >> 7;
      bucket_arr[lbase[b] + rank] = pk[k];
    }
  }
}

// Serial exclusive scan over 98 bucket counts; total -> row_ptr[N].
__global__ void scan_chunks_kernel(const int* __restrict__ cnt,
                                   int* __restrict__ off,
                                   int* __restrict__ row_ptr) {
  if (threadIdx.x == 0 && blockIdx.x == 0) {
    int run = 0;
    for (int i = 0; i < NCHUNK; ++i) { off[i] = run; run += cnt[i]; }
    row_ptr[N_NODES] = run;
  }
}

// Fused per-chunk: LDS histogram -> LDS scan -> row_ptr write -> scatter
// into final CSR order with LDS cursors.
__global__ __launch_bounds__(256) void build_csr_chunk(
    const int*  __restrict__ bucket_cnt,
    const int2* __restrict__ bucket_arr,
    const int*  __restrict__ chunk_off,
    int*  __restrict__ row_ptr,
    int2* __restrict__ edge_s) {
  __shared__ int lcnt[CHUNK];     // histogram, then cursors
  __shared__ int tsum[256];
  int b = blockIdx.x, t = threadIdx.x;
  for (int i = t; i < CHUNK; i += 256) lcnt[i] = 0;
  __syncthreads();
  int ne = bucket_cnt[b];
  const int2* ba = bucket_arr + (size_t)b * CAP;
  for (int i = t; i < ne; i += 256)
    atomicAdd(&lcnt[ba[i].x >> 18], 1);
  __syncthreads();
  // exclusive scan of 2048 counts (8 per thread + block scan of partials)
  int base = t * 8;
  int local[8];
  int s = 0;
#pragma unroll
  for (int k = 0; k < 8; ++k) { local[k] = lcnt[base + k]; s += local[k]; }
  tsum[t] = s;
  __syncthreads();
  for (int off = 1; off < 256; off <<= 1) {
    int v = (t >= off) ? tsum[t - off] : 0;
    __syncthreads();
    tsum[t] += v;
    __syncthreads();
  }
  int run = tsum[t] - s + chunk_off[b];
  int row0 = b * CHUNK;
#pragma unroll
  for (int k = 0; k < 8; ++k) {
    int idx = base + k;
    if (row0 + idx < N_NODES) row_ptr[row0 + idx] = run;
    lcnt[idx] = run;              // global cursor for this row
    run += local[k];
  }
  __syncthreads();
  for (int i = t; i < ne; i += 256) {
    int2 ed = ba[i];
    int p = atomicAdd(&lcnt[ed.x >> 18], 1);
    edge_s[p] = make_int2(ed.x & 0x3FFFF, ed.y);
  }
}

// Row-parallel bf16 SpMM: 8 lanes/row, 16 B (8 bf16 dims) per lane,
// edge loop unrolled x4 -> 4 independent gathers in flight.
__global__ __launch_bounds__(256) void spmm_bf16_kernel(
    const int*  __restrict__ row_ptr,
    const int2* __restrict__ edge_s,
    const uint4* __restrict__ x,
    uint4*       __restrict__ y) {
  int t = blockIdx.x * 256 + threadIdx.x;
  int r = t >> 3;
  int j = t & 7;
  if (r >= N_NODES) return;
  int s = row_ptr[r];
  int e = row_ptr[r + 1];
  float a0 = 0.f, a1 = 0.f, a2 = 0.f, a3 = 0.f;
  float a4 = 0.f, a5 = 0.f, a6 = 0.f, a7 = 0.f;
  int k = s;
#define ACCUM(ED, XV) {                                   \
    float v = __int_as_float((ED).y);                     \
    a0 += v * bflo((XV).x); a1 += v * bfhi((XV).x);       \
    a2 += v * bflo((XV).y); a3 += v * bfhi((XV).y);       \
    a4 += v * bflo((XV).z); a5 += v * bfhi((XV).z);       \
    a6 += v * bflo((XV).w); a7 += v * bfhi((XV).w); }
  for (; k + 4 <= e; k += 4) {
    int2 e0 = edge_s[k];
    int2 e1 = edge_s[k + 1];
    int2 e2 = edge_s[k + 2];
    int2 e3 = edge_s[k + 3];
    uint4 x0 = x[(size_t)e0.x * DV8 + j];
    uint4 x1 = x[(size_t)e1.x * DV8 + j];
    uint4 x2 = x[(size_t)e2.x * DV8 + j];
    uint4 x3 = x[(size_t)e3.x * DV8 + j];
    ACCUM(e0, x0); ACCUM(e1, x1); ACCUM(e2, x2); ACCUM(e3, x3);
  }
  for (; k < e; ++k) {
    int2 ed = edge_s[k];
    uint4 xv = x[(size_t)ed.x * DV8 + j];
    ACCUM(ed, xv);
  }
#undef ACCUM
  uint4 o;
  o.x = ((unsigned)f2bf(a1) << 16) | f2bf(a0);
  o.y = ((unsigned)f2bf(a3) << 16) | f2bf(a2);
  o.z = ((unsigned)f2bf(a5) << 16) | f2bf(a4);
  o.w = ((unsigned)f2bf(a7) << 16) | f2bf(a6);
  y[t] = o;
}

// Final: out[rowmap(n)] = 0.25*(x0_fp32 + y1 + y2 + y3); zero item row 0.
__global__ __launch_bounds__(256) void final_kernel(
    const float4*  __restrict__ user_emb,
    const float4*  __restrict__ item_emb,
    const ushort4* __restrict__ y1,
    const ushort4* __restrict__ y2,
    const ushort4* __restrict__ y3,
    float4* __restrict__ out) {
  int idx = blockIdx.x * 256 + threadIdx.x;
  if (idx < DV) {
    out[(size_t)NUP1 * DV + idx] = make_float4(0.f, 0.f, 0.f, 0.f);
  }
  if (idx >= N_NODES * DV) return;
  int n = idx >> 4;
  int j = idx & 15;
  float4 v = (n < NUP1) ? user_emb[idx]
                        : item_emb[(size_t)(n - 100000) * DV + j];
  ushort4 a = y1[idx], b = y2[idx], c = y3[idx];
  float4 o;
  o.x = 0.25f * (v.x + bf2f(a.x) + bf2f(b.x) + bf2f(c.x));
  o.y = 0.25f * (v.y + bf2f(a.y) + bf2f(b.y) + bf2f(c.y));
  o.z = 0.25f * (v.z + bf2f(a.z) + bf2f(b.z) + bf2f(c.z));
  o.w = 0.25f * (v.w + bf2f(a.w) + bf2f(b.w) + bf2f(c.w));
  int rm = (n < NUP1) ? n : n + 1;
  out[(size_t)rm * DV + j] = o;
}

static inline char* align16(char* p) {
  return (char*)(((uintptr_t)p + 15) & ~(uintptr_t)15);
}

extern "C" void kernel_launch(void* const* d_in, const int* in_sizes, int n_in,
                              void* d_out, int out_size, void* d_ws, size_t ws_size,
                              hipStream_t stream) {
  const float* user_emb = (const float*)d_in[0];
  const float* item_emb = (const float*)d_in[1];
  const int*   rows     = (const int*)d_in[2];
  const int*   cols     = (const int*)d_in[3];
  const float* vals     = (const float*)d_in[4];
  const int    nnz      = in_sizes[2];

  const size_t xbytes = (size_t)N_NODES * D * sizeof(unsigned short); // 25.6 MB
  char* p = (char*)d_ws;
  ushort4* x0 = (ushort4*)p;  p += xbytes;
  ushort4* y1 = (ushort4*)p;  p += xbytes;
  ushort4* y2 = (ushort4*)p;  p += xbytes;
  ushort4* y3 = (ushort4*)p;  p += xbytes;
  // bucket_arr aliases y2+y3 (51.2 MB window; needs 19.3 MB): fully consumed
  // by build_csr_chunk before layer-2 spmm writes y2.
  int2* bucket_arr = (int2*)y2;
  p = align16(p);
  int2* edge_s = (int2*)p;    p += (size_t)nnz * sizeof(int2);
  p = align16(p);
  int* row_ptr = (int*)p;     p += (size_t)(N_NODES + 1) * sizeof(int);
  p = align16(p);
  int* chunk_off = (int*)p;   p += (size_t)NCHUNK * sizeof(int);
  p = align16(p);
  int* bucket_cnt = (int*)p;  p += (size_t)NCHUNK * sizeof(int);

  float* out = (float*)d_out;

  const int row_elems = N_NODES * DV;               // 3,200,016
  const int node_grid = (row_elems + 255) / 256;    // 12501
  const int spmm_grid = (N_NODES * DV8 + 255) / 256; // 6251
  const int tile_grid = (nnz + T_TILE - 1) / T_TILE;

  init_kernel<<<node_grid, 256, 0, stream>>>(
      (const float4*)user_emb, (const float4*)item_emb, x0, bucket_cnt);
  pass1_bucket<<<tile_grid, 256, 0, stream>>>(
      rows, cols, vals, bucket_cnt, bucket_arr, nnz);
  scan_chunks_kernel<<<1, 64, 0, stream>>>(bucket_cnt, chunk_off, row_ptr);
  build_csr_chunk<<<NCHUNK, 256, 0, stream>>>(
      bucket_cnt, bucket_arr, chunk_off, row_ptr, edge_s);

  spmm_bf16_kernel<<<spmm_grid, 256, 0, stream>>>(
      row_ptr, edge_s, (const uint4*)x0, (uint4*)y1);
  spmm_bf16_kernel<<<spmm_grid, 256, 0, stream>>>(
      row_ptr, edge_s, (const uint4*)y1, (uint4*)y2);
  spmm_bf16_kernel<<<spmm_grid, 256, 0, stream>>>(
      row_ptr, edge_s, (const uint4*)y2, (uint4*)y3);

  final_kernel<<<node_grid, 256, 0, stream>>>(
      (const float4*)user_emb, (const float4*)item_emb, y1, y2, y3,
      (float4*)out);
}

// Round 6
// 325.997 us; speedup vs baseline: 16.1210x; 1.1187x over previous
//
#include <hip/hip_runtime.h>

// LightGCN, 3-layer propagation, 200001 nodes, D=64.
// Round 6: CHUNK 2048->512 (NCHUNK 98->391: 4x build_csr parallelism),
// parallel chunk-offset scan, spmm clamped-group-of-8 edge loop
// (no serial remainder; 16 loads in flight per iteration).

#define N_NODES 200001
#define NUP1    100001            // NUM_USERS + 1
#define D       64
#define DV      16                // float4/ushort4 per row (init/final)
#define DV8     8                 // uint4 (8 bf16) per row (spmm)
#define CHUNK   512
#define NCHUNK  ((N_NODES + CHUNK - 1) / CHUNK)   // 391
#define T_TILE  4096              // edges per pass1 block
#define EPT     16                // edges per thread in pass1
#define CAP     6144              // bucket capacity (exp ~5115, +14 sigma)

__device__ __forceinline__ unsigned short f2bf(float f) {
  unsigned u = __float_as_uint(f);
  unsigned r = (u + 0x7FFFu + ((u >> 16) & 1u)) >> 16;   // RNE
  return (unsigned short)r;
}
__device__ __forceinline__ float bf2f(unsigned short h) {
  return __uint_as_float(((unsigned)h) << 16);
}
__device__ __forceinline__ float bflo(unsigned u) { return __uint_as_float(u << 16); }
__device__ __forceinline__ float bfhi(unsigned u) { return __uint_as_float(u & 0xFFFF0000u); }

// Build x0 (bf16) from fp32 embeddings; also zero bucket_cnt.
__global__ __launch_bounds__(256) void init_kernel(
    const float4* __restrict__ user_emb,
    const float4* __restrict__ item_emb,
    ushort4* __restrict__ x0,
    int* __restrict__ bucket_cnt) {
  int idx = blockIdx.x * 256 + threadIdx.x;
  if (idx < NCHUNK) bucket_cnt[idx] = 0;
  if (idx >= N_NODES * DV) return;
  int n = idx >> 4;
  int j = idx & 15;
  float4 v = (n < NUP1) ? user_emb[idx]
                        : item_emb[(size_t)(n - 100000) * DV + j];
  x0[idx] = make_ushort4(f2bf(v.x), f2bf(v.y), f2bf(v.z), f2bf(v.w));
}

// Pass 1: multisplit edges into 391 chunk-buckets (private per-block runs).
__global__ __launch_bounds__(256) void pass1_bucket(
    const int*   __restrict__ rows,
    const int*   __restrict__ cols,
    const float* __restrict__ vals,
    int*  __restrict__ bucket_cnt,
    int2* __restrict__ bucket_arr,
    int nnz) {
  __shared__ int lcount[NCHUNK];
  __shared__ int lbase[NCHUNK];
  int t = threadIdx.x;
  for (int i = t; i < NCHUNK; i += 256) lcount[i] = 0;
  __syncthreads();
  long base = (long)blockIdx.x * T_TILE;
  int2 pk[EPT];
  int  meta[EPT];
#pragma unroll
  for (int k = 0; k < EPT; ++k) {
    long e = base + t + (long)k * 256;
    if (e < nnz) {
      int r = rows[e];
      int b = r >> 9;                          // chunk bucket (0..390)
      int rank = atomicAdd(&lcount[b], 1);     // LDS atomic
      pk[k] = make_int2(((r & 511) << 18) | cols[e], __float_as_int(vals[e]));
      meta[k] = (rank << 9) | b;               // rank<4096 (12b) | b (9b)
    } else {
      meta[k] = -1;
    }
  }
  __syncthreads();
  for (int b = t; b < NCHUNK; b += 256) {
    int c = lcount[b];
    lbase[b] = (c > 0) ? (b * CAP + atomicAdd(&bucket_cnt[b], c)) : 0;
  }
  __syncthreads();
#pragma unroll
  for (int k = 0; k < EPT; ++k) {
    if (meta[k] >= 0) {
      int b = meta[k] & 511;
      int rank = meta[k] >> 9;
      bucket_arr[lbase[b] + rank] = pk[k];
    }
  }
}

// Parallel exclusive scan of 391 bucket counts (one 512-thread block).
__global__ __launch_bounds__(512) void scan_chunks_kernel(
    const int* __restrict__ cnt, int* __restrict__ off,
    int* __restrict__ row_ptr, int nnz) {
  __shared__ int sh[512];
  int t = threadIdx.x;
  int v = (t < NCHUNK) ? cnt[t] : 0;
  sh[t] = v;
  __syncthreads();
  for (int o = 1; o < 512; o <<= 1) {
    int u = (t >= o) ? sh[t - o] : 0;
    __syncthreads();
    sh[t] += u;
    __syncthreads();
  }
  if (t < NCHUNK) off[t] = sh[t] - v;   // exclusive prefix
  if (t == 0) row_ptr[N_NODES] = nnz;
}

// Fused per-chunk: LDS histogram -> LDS scan -> row_ptr write -> scatter
// into final CSR order with LDS cursors.
__global__ __launch_bounds__(256) void build_csr_chunk(
    const int*  __restrict__ bucket_cnt,
    const int2* __restrict__ bucket_arr,
    const int*  __restrict__ chunk_off,
    int*  __restrict__ row_ptr,
    int2* __restrict__ edge_s) {
  __shared__ int lcnt[CHUNK];     // histogram, then cursors
  __shared__ int tsum[256];
  int b = blockIdx.x, t = threadIdx.x;
  lcnt[t] = 0; lcnt[t + 256] = 0;
  __syncthreads();
  int ne = bucket_cnt[b];
  const int2* ba = bucket_arr + (size_t)b * CAP;
  for (int i = t; i < ne; i += 256)
    atomicAdd(&lcnt[ba[i].x >> 18], 1);
  __syncthreads();
  int base = t * 2;
  int l0 = lcnt[base], l1 = lcnt[base + 1];
  int s = l0 + l1;
  tsum[t] = s;
  __syncthreads();
  for (int o = 1; o < 256; o <<= 1) {
    int v = (t >= o) ? tsum[t - o] : 0;
    __syncthreads();
    tsum[t] += v;
    __syncthreads();
  }
  int run = tsum[t] - s + chunk_off[b];
  int row0 = b * CHUNK;
  if (row0 + base < N_NODES) row_ptr[row0 + base] = run;
  lcnt[base] = run;
  run += l0;
  if (row0 + base + 1 < N_NODES) row_ptr[row0 + base + 1] = run;
  lcnt[base + 1] = run;
  __syncthreads();
  for (int i = t; i < ne; i += 256) {
    int2 ed = ba[i];
    int p = atomicAdd(&lcnt[ed.x >> 18], 1);
    edge_s[p] = make_int2(ed.x & 0x3FFFF, ed.y);
  }
}

// Row-parallel bf16 SpMM: 8 lanes/row, 16 B (8 bf16 dims) per lane.
// Edge loop in clamped groups of 8: 8 record loads + 8 gathers issued
// back-to-back every iteration; padded slots contribute v=0.
__global__ __launch_bounds__(256) void spmm_bf16_kernel(
    const int*  __restrict__ row_ptr,
    const int2* __restrict__ edge_s,
    const uint4* __restrict__ x,
    uint4*       __restrict__ y) {
  int t = blockIdx.x * 256 + threadIdx.x;
  int r = t >> 3;
  int j = t & 7;
  if (r >= N_NODES) return;
  int s = row_ptr[r];
  int e = row_ptr[r + 1];
  float a0 = 0.f, a1 = 0.f, a2 = 0.f, a3 = 0.f;
  float a4 = 0.f, a5 = 0.f, a6 = 0.f, a7 = 0.f;
  int last = e - 1;
#define ACCUM(V, XV) {                                    \
    a0 += (V) * bflo((XV).x); a1 += (V) * bfhi((XV).x);   \
    a2 += (V) * bflo((XV).y); a3 += (V) * bfhi((XV).y);   \
    a4 += (V) * bflo((XV).z); a5 += (V) * bfhi((XV).z);   \
    a6 += (V) * bflo((XV).w); a7 += (V) * bfhi((XV).w); }
  for (int g = s; g < e; g += 8) {
    int2 e0 = edge_s[min(g + 0, last)];
    int2 e1 = edge_s[min(g + 1, last)];
    int2 e2 = edge_s[min(g + 2, last)];
    int2 e3 = edge_s[min(g + 3, last)];
    int2 e4 = edge_s[min(g + 4, last)];
    int2 e5 = edge_s[min(g + 5, last)];
    int2 e6 = edge_s[min(g + 6, last)];
    int2 e7 = edge_s[min(g + 7, last)];
    uint4 x0 = x[(size_t)e0.x * DV8 + j];
    uint4 x1 = x[(size_t)e1.x * DV8 + j];
    uint4 x2 = x[(size_t)e2.x * DV8 + j];
    uint4 x3 = x[(size_t)e3.x * DV8 + j];
    uint4 x4 = x[(size_t)e4.x * DV8 + j];
    uint4 x5 = x[(size_t)e5.x * DV8 + j];
    uint4 x6 = x[(size_t)e6.x * DV8 + j];
    uint4 x7 = x[(size_t)e7.x * DV8 + j];
    float v0 = __int_as_float(e0.y);
    float v1 = (g + 1 < e) ? __int_as_float(e1.y) : 0.f;
    float v2 = (g + 2 < e) ? __int_as_float(e2.y) : 0.f;
    float v3 = (g + 3 < e) ? __int_as_float(e3.y) : 0.f;
    float v4 = (g + 4 < e) ? __int_as_float(e4.y) : 0.f;
    float v5 = (g + 5 < e) ? __int_as_float(e5.y) : 0.f;
    float v6 = (g + 6 < e) ? __int_as_float(e6.y) : 0.f;
    float v7 = (g + 7 < e) ? __int_as_float(e7.y) : 0.f;
    ACCUM(v0, x0); ACCUM(v1, x1); ACCUM(v2, x2); ACCUM(v3, x3);
    ACCUM(v4, x4); ACCUM(v5, x5); ACCUM(v6, x6); ACCUM(v7, x7);
  }
#undef ACCUM
  uint4 o;
  o.x = ((unsigned)f2bf(a1) << 16) | f2bf(a0);
  o.y = ((unsigned)f2bf(a3) << 16) | f2bf(a2);
  o.z = ((unsigned)f2bf(a5) << 16) | f2bf(a4);
  o.w = ((unsigned)f2bf(a7) << 16) | f2bf(a6);
  y[t] = o;
}

// Final: out[rowmap(n)] = 0.25*(x0_fp32 + y1 + y2 + y3); zero item row 0.
__global__ __launch_bounds__(256) void final_kernel(
    const float4*  __restrict__ user_emb,
    const float4*  __restrict__ item_emb,
    const ushort4* __restrict__ y1,
    const ushort4* __restrict__ y2,
    const ushort4* __restrict__ y3,
    float4* __restrict__ out) {
  int idx = blockIdx.x * 256 + threadIdx.x;
  if (idx < DV) {
    out[(size_t)NUP1 * DV + idx] = make_float4(0.f, 0.f, 0.f, 0.f);
  }
  if (idx >= N_NODES * DV) return;
  int n = idx >> 4;
  int j = idx & 15;
  float4 v = (n < NUP1) ? user_emb[idx]
                        : item_emb[(size_t)(n - 100000) * DV + j];
  ushort4 a = y1[idx], b = y2[idx], c = y3[idx];
  float4 o;
  o.x = 0.25f * (v.x + bf2f(a.x) + bf2f(b.x) + bf2f(c.x));
  o.y = 0.25f * (v.y + bf2f(a.y) + bf2f(b.y) + bf2f(c.y));
  o.z = 0.25f * (v.z + bf2f(a.z) + bf2f(b.z) + bf2f(c.z));
  o.w = 0.25f * (v.w + bf2f(a.w) + bf2f(b.w) + bf2f(c.w));
  int rm = (n < NUP1) ? n : n + 1;
  out[(size_t)rm * DV + j] = o;
}

static inline char* align16(char* p) {
  return (char*)(((uintptr_t)p + 15) & ~(uintptr_t)15);
}

extern "C" void kernel_launch(void* const* d_in, const int* in_sizes, int n_in,
                              void* d_out, int out_size, void* d_ws, size_t ws_size,
                              hipStream_t stream) {
  const float* user_emb = (const float*)d_in[0];
  const float* item_emb = (const float*)d_in[1];
  const int*   rows     = (const int*)d_in[2];
  const int*   cols     = (const int*)d_in[3];
  const float* vals     = (const float*)d_in[4];
  const int    nnz      = in_sizes[2];

  const size_t xbytes = (size_t)N_NODES * D * sizeof(unsigned short); // 25.6 MB
  char* p = (char*)d_ws;
  ushort4* x0 = (ushort4*)p;  p += xbytes;
  ushort4* y1 = (ushort4*)p;  p += xbytes;
  ushort4* y2 = (ushort4*)p;  p += xbytes;
  ushort4* y3 = (ushort4*)p;  p += xbytes;
  // bucket_arr aliases y2+y3 (51.2 MB window; needs 19.2 MB): fully consumed
  // by build_csr_chunk before layer-2 spmm writes y2.
  int2* bucket_arr = (int2*)y2;
  p = align16(p);
  int2* edge_s = (int2*)p;    p += (size_t)nnz * sizeof(int2);
  p = align16(p);
  int* row_ptr = (int*)p;     p += (size_t)(N_NODES + 1) * sizeof(int);
  p = align16(p);
  int* chunk_off = (int*)p;   p += (size_t)NCHUNK * sizeof(int);
  p = align16(p);
  int* bucket_cnt = (int*)p;  p += (size_t)NCHUNK * sizeof(int);

  float* out = (float*)d_out;

  const int row_elems = N_NODES * DV;                // 3,200,016
  const int node_grid = (row_elems + 255) / 256;     // 12501
  const int spmm_grid = (N_NODES * DV8 + 255) / 256; // 6251
  const int tile_grid = (nnz + T_TILE - 1) / T_TILE;

  init_kernel<<<node_grid, 256, 0, stream>>>(
      (const float4*)user_emb, (const float4*)item_emb, x0, bucket_cnt);
  pass1_bucket<<<tile_grid, 256, 0, stream>>>(
      rows, cols, vals, bucket_cnt, bucket_arr, nnz);
  scan_chunks_kernel<<<1, 512, 0, stream>>>(bucket_cnt, chunk_off, row_ptr, nnz);
  build_csr_chunk<<<NCHUNK, 256, 0, stream>>>(
      bucket_cnt, bucket_arr, chunk_off, row_ptr, edge_s);

  spmm_bf16_kernel<<<spmm_grid, 256, 0, stream>>>(
      row_ptr, edge_s, (const uint4*)x0, (uint4*)y1);
  spmm_bf16_kernel<<<spmm_grid, 256, 0, stream>>>(
      row_ptr, edge_s, (const uint4*)y1, (uint4*)y2);
  spmm_bf16_kernel<<<spmm_grid, 256, 0, stream>>>(
      row_ptr, edge_s, (const uint4*)y2, (uint4*)y3);

  final_kernel<<<node_grid, 256, 0, stream>>>(
      (const float4*)user_emb, (const float4*)item_emb, y1, y2, y3,
      (float4*)out);
}